// Round 8
// baseline (7813.215 us; speedup 1.0000x reference)
//
#include <hip/hip_runtime.h>
#include <hip/hip_bf16.h>

typedef __attribute__((ext_vector_type(8))) short   short8;
typedef __attribute__((ext_vector_type(4))) float   float4_;
typedef __attribute__((ext_vector_type(2))) float   float2_;

// ---------------- workspace layout (bytes) ----------------
#define WPACK_OFF   0
#define WPACK_BYTES 786432                    // 1024 rows x 384 k x 2B, A-frag packed
#define HBUF_OFF    786432
#define HBUF_BYTES  4194304                   // 32 slots x 16grp x 16b x 256k x bf16
#define BIAS_OFF    (HBUF_OFF + HBUF_BYTES)   // 4980736
#define BIAS_BYTES  4096
#define FLAGS_OFF   (BIAS_OFF + BIAS_BYTES)   // 4984832
#define FLAGS_BYTES 2048                      // 16 groups x 32-int padded counters

#define SLOT_ULL 16384                        // ulls per step-slot (16grp*16b*64)
#define SLOT_U32 32768                        // uints per step-slot
#define SENT_U32 0xFFFFFFFFu                  // bf16 NaN x2 — unreachable for finite h

__device__ __forceinline__ unsigned short f2bf(float f) {
  unsigned int u = __float_as_uint(f);
  u += 0x7fffu + ((u >> 16) & 1u);            // round-to-nearest-even
  return (unsigned short)(u >> 16);
}

// Pack W = [W_hh | W_ih] into MFMA A-fragment order, bf16.
// idx = ((((s*4+w)*2+m)*12)+kt)*64+lane ; block s owns rows gate*256 + [s*32,s*32+32).
__global__ void pack_w(const float* __restrict__ w_ih,
                       const float* __restrict__ w_hh,
                       unsigned short* __restrict__ wpack) {
  int idx = blockIdx.x * blockDim.x + threadIdx.x;
  if (idx >= 49152) return;
  int lane = idx & 63;
  int r1 = idx >> 6;
  int kt = r1 % 12;
  int r2 = r1 / 12;
  int m  = r2 & 1;          // mtile within slice (16 rows)
  int r3 = r2 >> 1;
  int w  = r3 & 3;          // gate (i,f,g,o) == wave
  int s  = r3 >> 2;         // slice 0..7
  int row = w * 256 + s * 32 + m * 16 + (lane & 15);
  int q = lane >> 4;
  short8 o;
#pragma unroll
  for (int j = 0; j < 8; ++j) {
    int kk = kt * 32 + q * 8 + j;             // 0..383
    float v = (kt < 8) ? w_hh[row * 256 + kk]
                       : w_ih[row * 128 + (kk - 256)];
    o[j] = (short)f2bf(v);
  }
  *(short8*)(wpack + (size_t)idx * 8) = o;
}

// Fill hbuf: slot 0 = bf16(h0), slots 1..31 = sentinel. Also bias = b_ih+b_hh.
__global__ void init_hb(const float* __restrict__ h0,
                        const float* __restrict__ b_ih,
                        const float* __restrict__ b_hh,
                        unsigned long long* __restrict__ hbuf,
                        float* __restrict__ bias) {
  int idx = blockIdx.x * blockDim.x + threadIdx.x;
  if (idx < 16384) {                           // slot 0: seed h0 (4 halves per ull)
    unsigned long long v = 0;
#pragma unroll
    for (int e = 0; e < 4; ++e)
      v |= (unsigned long long)f2bf(h0[idx * 4 + e]) << (16 * e);
    hbuf[idx] = v;
  } else if (idx < 524288) {                   // slots 1..31: sentinel
    hbuf[idx] = 0xFFFFFFFFFFFFFFFFull;
  } else if (idx < 525312) {
    int j = idx - 524288;
    bias[j] = b_ih[j] + b_hh[j];
  }
}

__device__ __forceinline__ float sigm_(float v) {
  return 1.f / (1.f + __expf(-v));
}
__device__ __forceinline__ float tanh_(float v) {
  return 1.f - 2.f / (__expf(2.f * v) + 1.f);  // robust at +-inf
}

__global__ __launch_bounds__(256, 1) void lstm_main(
    const float* __restrict__ x, const float* __restrict__ c0,
    const unsigned short* __restrict__ wpack, const float* __restrict__ bias,
    unsigned long long* hbuf, int* flags, float* __restrict__ out) {

  const int tid  = threadIdx.x;
  const int w    = tid >> 6;       // wave == gate 0..3
  const int lane = tid & 63;
  const int q    = lane >> 4;
  const int bl   = lane & 15;

  const int id  = blockIdx.x;
  const int grp = id >> 3;                  // batch group 0..15
  const int s   = id & 7;                   // n-slice 0..7 (32 elems)

  // combiner-role constants: thread (np,b) owns h/c for n = s*32+2np+{0,1}, batch b
  const int np = tid >> 4;                  // 0..15
  const int b  = tid & 15;
  const int nglob   = s * 32 + 2 * np;
  const int bglob_c = grp * 16 + b;

  // ---- W fragments in VGPRs: 2 mtiles x 12 ktiles = 24 frags (96 regs) ----
  short8 wf[24];
  {
    const unsigned short* base =
        wpack + ((size_t)((s * 4 + w) * 24) * 64 + lane) * 8;
#pragma unroll
    for (int f = 0; f < 24; ++f)
      wf[f] = *(const short8*)(base + (size_t)f * 64 * 8);
  }
#pragma unroll
  for (int f = 0; f < 24; ++f)
    asm volatile("" : "+v"(wf[f]));          // 96 pinned + ~130 live < 256: safe

  // bias for gate w (acc init)
  float4_ bia[2];
#pragma unroll
  for (int m = 0; m < 2; ++m)
    bia[m] = *(const float4_*)(bias + w * 256 + s * 32 + m * 16 + q * 4);

  // c state (combiner role)
  float cst[2];
  cst[0] = c0[(size_t)bglob_c * 256 + nglob];
  cst[1] = c0[(size_t)bglob_c * 256 + nglob + 1];

  // x prefetch for t=0 (ktiles 8..11); B-frag batch = grp*16+bl
  // NON-TEMPORAL: x is read-once streaming — do not allocate in LLC, keep
  // the LLC resident for hbuf (the latency-critical sync medium).
  float4_ xr[8];
  {
    const float4_* xb = (const float4_*)(x + (size_t)(grp * 16 + bl) * 131072 + q * 8);
#pragma unroll
    for (int kx = 0; kx < 4; ++kx) {
      xr[kx * 2]     = __builtin_nontemporal_load(xb + kx * 8);
      xr[kx * 2 + 1] = __builtin_nontemporal_load(xb + kx * 8 + 1);
    }
  }

  // hbuf addressing
  const size_t hb_base = ((size_t)grp * 16 + bl) * 64;            // consumer (ull)
  const size_t my_u32  = ((size_t)grp * 16 + b) * 128 + s * 16 + np;  // producer (uint)
  unsigned int* const hbuf32 = (unsigned int*)hbuf;
  int* const cnt = &flags[grp * 32];

  // gate-exchange LDS: [gate][n_local 32][b 16+pad]
  __shared__ float glds[4][32][17];

  float hout[2];

#pragma unroll 1
  for (int t = 0; t < 1024; ++t) {
    // convert prefetched x -> bf16 frags (xr issued ~a full step ago)
    short8 xf[4];
#pragma unroll
    for (int kx = 0; kx < 4; ++kx) {
      short8 v;
#pragma unroll
      for (int e = 0; e < 4; ++e) {
        v[e]     = (short)f2bf(xr[kx * 2][e]);
        v[e + 4] = (short)f2bf(xr[kx * 2 + 1][e]);
      }
      xf[kx] = v;
    }

    // ---- poll h_t (data-embedded sync; the poll IS the load) ----
    // Each 8B ull holds two independently-produced 4B chunks: check both halves.
    unsigned long long pl[16];
    {
      unsigned long long* hb =
          hbuf + (size_t)(t & 31) * SLOT_ULL + hb_base + q * 2;
      for (;;) {
#pragma unroll
        for (int kt = 0; kt < 8; ++kt) {
          pl[kt * 2]     = __hip_atomic_load(hb + kt * 8,     __ATOMIC_RELAXED, __HIP_MEMORY_SCOPE_AGENT);
          pl[kt * 2 + 1] = __hip_atomic_load(hb + kt * 8 + 1, __ATOMIC_RELAXED, __HIP_MEMORY_SCOPE_AGENT);
        }
        bool ok = true;
#pragma unroll
        for (int i = 0; i < 16; ++i) {
          ok &= ((unsigned)(pl[i] & 0xFFFFull) != 0xFFFFu);
          ok &= ((unsigned)((pl[i] >> 32) & 0xFFFFull) != 0xFFFFu);
        }
        if (__all(ok)) break;
        __builtin_amdgcn_s_sleep(1);
      }
    }
    asm volatile("" ::: "memory");   // nothing hoists above the poll

    float4_ acc[2];
#pragma unroll
    for (int m = 0; m < 2; ++m) acc[m] = bia[m];

    // x contribution: ktiles 8..11
#pragma unroll
    for (int kx = 0; kx < 4; ++kx)
#pragma unroll
      for (int m = 0; m < 2; ++m)
        acc[m] = __builtin_amdgcn_mfma_f32_16x16x32_bf16(wf[m * 12 + 8 + kx], xf[kx], acc[m], 0, 0, 0);

    // h contribution: ktiles 0..7
#pragma unroll
    for (int kt = 0; kt < 8; ++kt) {
      union { unsigned long long u[2]; short8 v; } uu;
      uu.u[0] = pl[kt * 2];
      uu.u[1] = pl[kt * 2 + 1];
#pragma unroll
      for (int m = 0; m < 2; ++m)
        acc[m] = __builtin_amdgcn_mfma_f32_16x16x32_bf16(wf[m * 12 + kt], uu.v, acc[m], 0, 0, 0);
    }

    // publish gate-w pre-activations to LDS (C-layout: col=bl, row=q*4+r)
#pragma unroll
    for (int m = 0; m < 2; ++m)
#pragma unroll
      for (int r = 0; r < 4; ++r)
        glds[w][m * 16 + q * 4 + r][bl] = acc[m][r];

    __syncthreads();

    // x prefetch for NEXT step — after the barrier so no waitcnt drains it
    // early; NON-TEMPORAL (streaming, no LLC allocation).
    {
      int tn = (t < 1023) ? (t + 1) : 1023;
      const float4_* xb = (const float4_*)(x + (size_t)(grp * 16 + bl) * 131072 +
                                           (size_t)tn * 128 + q * 8);
#pragma unroll
      for (int kx = 0; kx < 4; ++kx) {
        xr[kx * 2]     = __builtin_nontemporal_load(xb + kx * 8);
        xr[kx * 2 + 1] = __builtin_nontemporal_load(xb + kx * 8 + 1);
      }
    }

    // ---- combine all 4 gates for this thread's 2 (n,b) elements ----
    unsigned short hp[2];
#pragma unroll
    for (int dn = 0; dn < 2; ++dn) {
      int nl = 2 * np + dn;
      float iv = sigm_(glds[0][nl][b]);
      float fv = sigm_(glds[1][nl][b]);
      float gv = tanh_(glds[2][nl][b]);
      float ov = sigm_(glds[3][nl][b]);
      float cv = fv * cst[dn] + iv * gv;
      cst[dn] = cv;
      float hv = ov * tanh_(cv);
      hout[dn] = hv;
      hp[dn] = f2bf(hv);
    }

    // write h_{t+1} chunk: ONE 4B atomic store per thread
    {
      unsigned int hu = (unsigned int)hp[0] | ((unsigned int)hp[1] << 16);
      unsigned int* dst = hbuf32 + (size_t)((t + 1) & 31) * SLOT_U32 + my_u32;
      __hip_atomic_store(dst, hu, __ATOMIC_RELAXED, __HIP_MEMORY_SCOPE_AGENT);
    }

    // ---- every 8 steps: reset old slots + group barrier (amortized) ----
    if ((t & 7) == 7 && t != 1023) {
      const int k = t >> 3;                 // t == 8k+7
#pragma unroll
      for (int j = 0; j < 8; ++j) {
        int m = 8 * k - 15 + j;             // steps consumed >= 2 windows ago
        if (m >= 0) {
          unsigned int* rp = hbuf32 + (size_t)(m & 31) * SLOT_U32 + my_u32;
          __hip_atomic_store(rp, SENT_U32, __ATOMIC_RELAXED, __HIP_MEMORY_SCOPE_AGENT);
        }
      }
      __syncthreads();                      // drain whole block's stores (vmcnt0)
      if (tid == 0)
        __hip_atomic_fetch_add(cnt, 1, __ATOMIC_RELEASE, __HIP_MEMORY_SCOPE_AGENT);
      const int target = 8 * (k + 1);       // 8 blocks per group
      for (;;) {
        int v = __hip_atomic_load(cnt, __ATOMIC_RELAXED, __HIP_MEMORY_SCOPE_AGENT);
        if (v >= target) break;
        __builtin_amdgcn_s_sleep(1);
      }
      __builtin_amdgcn_fence(__ATOMIC_ACQUIRE, "agent");
    }
  }

  // final h (fp32) -> d_out [1,B,H]
  {
    float2_ o2; o2[0] = hout[0]; o2[1] = hout[1];
    *(float2_*)(out + (size_t)bglob_c * 256 + nglob) = o2;
  }
}

extern "C" void kernel_launch(void* const* d_in, const int* in_sizes, int n_in,
                              void* d_out, int out_size, void* d_ws, size_t ws_size,
                              hipStream_t stream) {
  (void)in_sizes; (void)n_in; (void)out_size; (void)ws_size;
  const float* x    = (const float*)d_in[0];
  const float* h0   = (const float*)d_in[1];
  const float* c0   = (const float*)d_in[2];
  const float* w_ih = (const float*)d_in[3];
  const float* w_hh = (const float*)d_in[4];
  const float* b_ih = (const float*)d_in[5];
  const float* b_hh = (const float*)d_in[6];

  char* ws = (char*)d_ws;
  unsigned short*     wpack = (unsigned short*)(ws + WPACK_OFF);
  unsigned long long* hbuf  = (unsigned long long*)(ws + HBUF_OFF);
  float*              bias  = (float*)(ws + BIAS_OFF);
  int*                flags = (int*)(ws + FLAGS_OFF);

  hipMemsetAsync(flags, 0, FLAGS_BYTES, stream);
  pack_w<<<192, 256, 0, stream>>>(w_ih, w_hh, wpack);
  init_hb<<<2053, 256, 0, stream>>>(h0, b_ih, b_hh, hbuf, bias);
  lstm_main<<<128, 256, 0, stream>>>(x, c0, wpack, bias, hbuf, flags,
                                     (float*)d_out);
}